// Round 9
// baseline (373.924 us; speedup 1.0000x reference)
//
#include <hip/hip_runtime.h>
#include <hip/hip_bf16.h>

#define D_ 768
#define E_ 8
#define H_ 3072
#define N_TOK 4096
#define BM 128
#define BN 64
#define BK 64

typedef _Float16 f16;
typedef f16 f16x8 __attribute__((ext_vector_type(8)));
typedef float f32x4 __attribute__((ext_vector_type(4)));

__device__ __forceinline__ void gld16(const f16* g, f16* l) {
    __builtin_amdgcn_global_load_lds(
        (const __attribute__((address_space(1))) unsigned int*)g,
        (__attribute__((address_space(3))) unsigned int*)l, 16, 0, 0);
}

// ---------------- weight convert + transpose + swizzle: fp32 [R][C] -> fp16 [C][R] ----------------
// Output row c is XOR-16B-chunk swizzled: within each 64-half group, chunk k stored at k^(c&7).
#define TP 66
__global__ __launch_bounds__(256) void cvt_w_t(const float* __restrict__ in,
                                               f16* __restrict__ outp,
                                               int R, int C) {
    __shared__ f16 t[64][TP];
    const float* src = in + (size_t)blockIdx.z * R * C;
    f16* dst = outp + (size_t)blockIdx.z * R * C;
    int r0 = blockIdx.y * 64, c0 = blockIdx.x * 64;
    int tid = threadIdx.x;
    {
        int r = tid >> 4;
        int c = (tid & 15) * 4;
#pragma unroll
        for (int i = 0; i < 4; i++) {
            float4 v = *(const float4*)(src + (size_t)(r0 + r + i * 16) * C + (c0 + c));
            t[r + i * 16][c] = (f16)v.x;
            t[r + i * 16][c + 1] = (f16)v.y;
            t[r + i * 16][c + 2] = (f16)v.z;
            t[r + i * 16][c + 3] = (f16)v.w;
        }
    }
    __syncthreads();
    {
        int c = tid >> 3;
        int rr = (tid & 7) * 8;          // chunk-aligned 8-half span along R
        int ch = rr >> 3;                // 0..7 chunk within the 64-half group
#pragma unroll
        for (int i = 0; i < 2; i++) {
            int cc = c + i * 32;
            int rowi = c0 + cc;
            f16x8 o;
#pragma unroll
            for (int j = 0; j < 8; j++) o[j] = t[rr + j][cc];
            *(f16x8*)(dst + (size_t)rowi * R + r0 + (((ch ^ rowi) & 7) << 3)) = o;
        }
    }
}

// ---------------- router ----------------
__global__ __launch_bounds__(256) void router(const float* __restrict__ x,
                                              const float* __restrict__ gw,
                                              const float* __restrict__ gb,
                                              int* __restrict__ counts,
                                              int* __restrict__ list,
                                              float* __restrict__ wslot) {
    int wv = threadIdx.x >> 6;
    int lane = threadIdx.x & 63;
    int tok = blockIdx.x * 4 + wv;
    const float* xr = x + (size_t)tok * D_;
    float acc[E_];
#pragma unroll
    for (int e = 0; e < E_; e++) acc[e] = 0.f;
    for (int d = lane; d < D_; d += 64) {
        float v = xr[d];
        const float* g = gw + d * E_;
#pragma unroll
        for (int e = 0; e < E_; e++) acc[e] += v * g[e];
    }
#pragma unroll
    for (int e = 0; e < E_; e++) {
#pragma unroll
        for (int off = 32; off; off >>= 1) acc[e] += __shfl_xor(acc[e], off, 64);
    }
    if (lane == 0) {
        float v0 = -3.4e38f, v1 = -3.4e38f;
        int i0 = 0, i1 = 0;
#pragma unroll
        for (int e = 0; e < E_; e++) {
            float l = acc[e] + gb[e];
            if (l > v0) { v1 = v0; i1 = i0; v0 = l; i0 = e; }
            else if (l > v1) { v1 = l; i1 = e; }
        }
        float p1 = expf(v1 - v0);
        float s = 1.f + p1;
        int p0 = atomicAdd(&counts[i0], 1);
        list[i0 * N_TOK + p0] = tok * 2;
        int p1p = atomicAdd(&counts[i1], 1);
        list[i1 * N_TOK + p1p] = tok * 2 + 1;
        wslot[tok * 2] = 1.f / s;
        wslot[tok * 2 + 1] = p1 / s;
    }
}

// ---------------- prefix scan over 8 counts ----------------
__global__ void scan8(const int* __restrict__ counts, int* __restrict__ offs) {
    if (threadIdx.x == 0) {
        int s = 0;
#pragma unroll
        for (int e = 0; e < E_; e++) { offs[e] = s; s += counts[e]; }
        offs[E_] = s;
    }
}

// ---------------- pack A: gather token rows -> packed swizzled fp16 [8192][D] ----------------
__global__ __launch_bounds__(256) void pack_a(const float* __restrict__ x,
                                              const int* __restrict__ counts,
                                              const int* __restrict__ offs,
                                              const int* __restrict__ list,
                                              f16* __restrict__ xg) {
    int wv = threadIdx.x >> 6, lane = threadIdx.x & 63;
    int idx = blockIdx.x * 4 + wv;            // e*N_TOK + j
    int e = idx >> 12, j = idx & (N_TOK - 1);
    if (j >= counts[e]) return;
    int id = list[idx];
    int row = offs[e] + j;
    const float* xr = x + (size_t)(id >> 1) * D_;
    f16* dst = xg + (size_t)row * D_;
    int r7 = row & 7;
#pragma unroll
    for (int c = 0; c < 3; c++) {
        int h = lane * 4 + c * 256;
        float4 v = *(const float4*)(xr + h);
        f16 o[4] = {(f16)v.x, (f16)v.y, (f16)v.z, (f16)v.w};
        int hs = (h & ~0x3F) | ((((h >> 3) ^ r7) & 7) << 3) | (h & 7);
        *(float2*)(dst + hs) = *(const float2*)o;
    }
}

// ---------------- GEMM1: h = gelu(xg @ w1 + b1), 128x64 tiles, gld_lds ----------------
__global__ __launch_bounds__(256, 8) void gemm1(const f16* __restrict__ xg,
                                                const f16* __restrict__ w1t,
                                                const float* __restrict__ b1,
                                                const int* __restrict__ counts,
                                                const int* __restrict__ offs,
                                                f16* __restrict__ hbuf) {
    int e = blockIdx.z;
    int cnt = counts[e];
    int off = offs[e];
    int rb = blockIdx.y * BM;
    if (rb >= cnt) return;
    int cb = blockIdx.x * BN;

    __shared__ f16 lds[(BM + BN) * BK];   // A halfs [0,8192), B halfs [8192,12288)
    char* ldsb = (char*)lds;

    int tid = threadIdx.x;
    int wv = tid >> 6, lane = tid & 63;
    int lr = lane >> 3, lc = lane & 7;

    // A: 4 staging rounds (rows i*32 + wv*8 + lr), B: 2 rounds
    int agr[4];
    const f16* ap[4];
    const f16* bp[2];
    f16* la[4];
    f16* lb[2];
#pragma unroll
    for (int i = 0; i < 4; i++) {
        int r = i * 32 + wv * 8 + lr;
        int ag = off + rb + r; if (ag > 8191) ag = 8191;
        agr[i] = ag;
        ap[i] = xg + (size_t)ag * D_ + lc * 8;
        la[i] = lds + i * 2048 + wv * 512;
    }
    const f16* wb = w1t + (size_t)e * H_ * D_;
#pragma unroll
    for (int i = 0; i < 2; i++) {
        int r = i * 32 + wv * 8 + lr;
        bp[i] = wb + (size_t)(cb + r) * D_ + lc * 8;
        lb[i] = lds + 8192 + i * 2048 + wv * 512;
    }

    int fr = lane & 15, qh = lane >> 4;
    int koff = (off + rb) & 7;

    int roA[2][2], roB[4][2];
#pragma unroll
    for (int m = 0; m < 2; m++)
#pragma unroll
        for (int ks = 0; ks < 2; ks++) {
            int row = wv * 32 + m * 16 + fr;
            roA[m][ks] = row * 128 + ((((ks * 4 + qh) ^ (koff + row)) & 7) << 4);
        }
#pragma unroll
    for (int n = 0; n < 4; n++)
#pragma unroll
        for (int ks = 0; ks < 2; ks++) {
            int row = n * 16 + fr;
            roB[n][ks] = 16384 + row * 128 + ((((ks * 4 + qh) ^ row) & 7) << 4);
        }

    f32x4 acc[2][4] = {};
    const int NT = D_ / BK;  // 12
#pragma unroll 1
    for (int t = 0; t < NT; ++t) {
        int kk = t * BK;
#pragma unroll
        for (int i = 0; i < 4; i++) gld16(ap[i] + kk, la[i]);
#pragma unroll
        for (int i = 0; i < 2; i++) gld16(bp[i] + kk, lb[i]);
        __syncthreads();
#pragma unroll
        for (int ks = 0; ks < 2; ks++) {
            f16x8 af[2], bf[4];
#pragma unroll
            for (int m = 0; m < 2; m++) af[m] = *(const f16x8*)(ldsb + roA[m][ks]);
#pragma unroll
            for (int n = 0; n < 4; n++) bf[n] = *(const f16x8*)(ldsb + roB[n][ks]);
#pragma unroll
            for (int m = 0; m < 2; m++)
#pragma unroll
                for (int n = 0; n < 4; n++)
                    acc[m][n] = __builtin_amdgcn_mfma_f32_16x16x32_f16(af[m], bf[n], acc[m][n], 0, 0, 0);
        }
        __syncthreads();
    }

#pragma unroll
    for (int n = 0; n < 4; n++) {
        int colg = cb + n * 16 + fr;
        float bias = b1[e * H_ + colg];
#pragma unroll
        for (int m = 0; m < 2; m++) {
#pragma unroll
            for (int r = 0; r < 4; r++) {
                int j = rb + wv * 32 + m * 16 + qh * 4 + r;
                if (j < cnt) {
                    float v = acc[m][n][r] + bias;
                    v = 0.5f * v * (1.f + erff(v * 0.70710678f));
                    int row = off + j;
                    int hs = (colg & ~0x3F) | ((((colg >> 3) ^ row) & 7) << 3) | (colg & 7);
                    hbuf[(size_t)row * H_ + hs] = (f16)v;
                }
            }
        }
    }
}

// ---------------- GEMM2: y = (hbuf @ w2 + b2) * wslot, scatter-add ----------------
#define KSPLIT 2
#define KCH (H_ / KSPLIT)
__global__ __launch_bounds__(256, 8) void gemm2(const f16* __restrict__ hbuf,
                                                const f16* __restrict__ w2t,
                                                const float* __restrict__ b2,
                                                const int* __restrict__ counts,
                                                const int* __restrict__ offs,
                                                const int* __restrict__ list,
                                                const float* __restrict__ wslot,
                                                float* __restrict__ out) {
    int e = blockIdx.z;
    int cnt = counts[e];
    int off = offs[e];
    int rb = blockIdx.y * BM;
    if (rb >= cnt) return;
    int xk = blockIdx.x;                 // 0..23, fastest
    int cb = (xk % (D_ / BN)) * BN;
    int kz = xk / (D_ / BN);
    int k0 = kz * KCH;

    __shared__ f16 lds[(BM + BN) * BK];
    char* ldsb = (char*)lds;

    int tid = threadIdx.x;
    int wv = tid >> 6, lane = tid & 63;
    int lr = lane >> 3, lc = lane & 7;

    const f16* ap[4];
    const f16* bp[2];
    f16* la[4];
    f16* lb[2];
#pragma unroll
    for (int i = 0; i < 4; i++) {
        int r = i * 32 + wv * 8 + lr;
        int ag = off + rb + r; if (ag > 8191) ag = 8191;
        ap[i] = hbuf + (size_t)ag * H_ + k0 + lc * 8;
        la[i] = lds + i * 2048 + wv * 512;
    }
    const f16* wb = w2t + (size_t)e * D_ * H_;
#pragma unroll
    for (int i = 0; i < 2; i++) {
        int r = i * 32 + wv * 8 + lr;
        bp[i] = wb + (size_t)(cb + r) * H_ + k0 + lc * 8;
        lb[i] = lds + 8192 + i * 2048 + wv * 512;
    }

    int fr = lane & 15, qh = lane >> 4;
    int koff = (off + rb) & 7;

    int roA[2][2], roB[4][2];
#pragma unroll
    for (int m = 0; m < 2; m++)
#pragma unroll
        for (int ks = 0; ks < 2; ks++) {
            int row = wv * 32 + m * 16 + fr;
            roA[m][ks] = row * 128 + ((((ks * 4 + qh) ^ (koff + row)) & 7) << 4);
        }
#pragma unroll
    for (int n = 0; n < 4; n++)
#pragma unroll
        for (int ks = 0; ks < 2; ks++) {
            int row = n * 16 + fr;
            roB[n][ks] = 16384 + row * 128 + ((((ks * 4 + qh) ^ row) & 7) << 4);
        }

    f32x4 acc[2][4] = {};
    const int NT = KCH / BK;  // 24
#pragma unroll 1
    for (int t = 0; t < NT; ++t) {
        int kk = t * BK;
#pragma unroll
        for (int i = 0; i < 4; i++) gld16(ap[i] + kk, la[i]);
#pragma unroll
        for (int i = 0; i < 2; i++) gld16(bp[i] + kk, lb[i]);
        __syncthreads();
#pragma unroll
        for (int ks = 0; ks < 2; ks++) {
            f16x8 af[2], bf[4];
#pragma unroll
            for (int m = 0; m < 2; m++) af[m] = *(const f16x8*)(ldsb + roA[m][ks]);
#pragma unroll
            for (int n = 0; n < 4; n++) bf[n] = *(const f16x8*)(ldsb + roB[n][ks]);
#pragma unroll
            for (int m = 0; m < 2; m++)
#pragma unroll
                for (int n = 0; n < 4; n++)
                    acc[m][n] = __builtin_amdgcn_mfma_f32_16x16x32_f16(af[m], bf[n], acc[m][n], 0, 0, 0);
        }
        __syncthreads();
    }

#pragma unroll
    for (int n = 0; n < 4; n++) {
        int colg = cb + n * 16 + fr;
        float bias = (kz == 0) ? b2[e * D_ + colg] : 0.f;
#pragma unroll
        for (int m = 0; m < 2; m++) {
#pragma unroll
            for (int r = 0; r < 4; r++) {
                int j = rb + wv * 32 + m * 16 + qh * 4 + r;
                if (j < cnt) {
                    int id = list[e * N_TOK + j];
                    float w = wslot[id];
                    float v = (acc[m][n][r] + bias) * w;
                    atomicAdd(&out[(size_t)(id >> 1) * D_ + colg], v);
                }
            }
        }
    }
}

extern "C" void kernel_launch(void* const* d_in, const int* in_sizes, int n_in,
                              void* d_out, int out_size, void* d_ws, size_t ws_size,
                              hipStream_t stream) {
    const float* x = (const float*)d_in[0];
    const float* gate_w = (const float*)d_in[1];
    const float* gate_b = (const float*)d_in[2];
    const float* w1 = (const float*)d_in[3];
    const float* b1 = (const float*)d_in[4];
    const float* w2 = (const float*)d_in[5];
    const float* b2 = (const float*)d_in[6];
    float* out = (float*)d_out;

    char* ws = (char*)d_ws;
    int* counts = (int*)ws;                           // 32 B
    int* offs = (int*)(ws + 256);                     // 36 B
    int* list = (int*)(ws + 1024);                    // 131072 B
    float* wslot = (float*)(ws + 132096);             // 32768 B
    f16* xg = (f16*)(ws + 196608);                    // 12582912 B
    f16* w1t = (f16*)(ws + 12779520);                 // 37748736 B
    f16* w2t = (f16*)(ws + 50528256);                 // 37748736 B
    f16* hbuf = (f16*)(ws + 88276992);                // 50331648 B

    hipMemsetAsync(counts, 0, 256, stream);
    hipMemsetAsync(out, 0, (size_t)out_size * sizeof(float), stream);

    router<<<1024, 256, 0, stream>>>(x, gate_w, gate_b, counts, list, wslot);
    scan8<<<1, 64, 0, stream>>>(counts, offs);
    pack_a<<<E_ * N_TOK / 4, 256, 0, stream>>>(x, counts, offs, list, xg);
    cvt_w_t<<<dim3(H_ / 64, D_ / 64, E_), 256, 0, stream>>>(w1, w1t, D_, H_);
    cvt_w_t<<<dim3(D_ / 64, H_ / 64, E_), 256, 0, stream>>>(w2, w2t, H_, D_);
    gemm1<<<dim3(H_ / BN, N_TOK / BM, E_), 256, 0, stream>>>(xg, w1t, b1, counts, offs, hbuf);
    gemm2<<<dim3((D_ / BN) * KSPLIT, N_TOK / BM, E_), 256, 0, stream>>>(hbuf, w2t, b2, counts, offs, list, wslot, out);
}

// Round 10
// 369.325 us; speedup vs baseline: 1.0125x; 1.0125x over previous
//
#include <hip/hip_runtime.h>
#include <hip/hip_bf16.h>

#define D_ 768
#define E_ 8
#define H_ 3072
#define N_TOK 4096
#define BT 64
#define BK 64

typedef _Float16 f16;
typedef f16 f16x8 __attribute__((ext_vector_type(8)));
typedef float f32x4 __attribute__((ext_vector_type(4)));

__device__ __forceinline__ void gld16(const f16* g, f16* l) {
    __builtin_amdgcn_global_load_lds(
        (const __attribute__((address_space(1))) unsigned int*)g,
        (__attribute__((address_space(3))) unsigned int*)l, 16, 0, 0);
}

// ---------------- weight convert + transpose + swizzle: fp32 [R][C] -> fp16 [C][R] ----------------
#define TP 66
__global__ __launch_bounds__(256) void cvt_w_t(const float* __restrict__ in,
                                               f16* __restrict__ outp,
                                               int R, int C) {
    __shared__ f16 t[64][TP];
    const float* src = in + (size_t)blockIdx.z * R * C;
    f16* dst = outp + (size_t)blockIdx.z * R * C;
    int r0 = blockIdx.y * 64, c0 = blockIdx.x * 64;
    int tid = threadIdx.x;
    {
        int r = tid >> 4;
        int c = (tid & 15) * 4;
#pragma unroll
        for (int i = 0; i < 4; i++) {
            float4 v = *(const float4*)(src + (size_t)(r0 + r + i * 16) * C + (c0 + c));
            t[r + i * 16][c] = (f16)v.x;
            t[r + i * 16][c + 1] = (f16)v.y;
            t[r + i * 16][c + 2] = (f16)v.z;
            t[r + i * 16][c + 3] = (f16)v.w;
        }
    }
    __syncthreads();
    {
        int c = tid >> 3;
        int rr = (tid & 7) * 8;
        int ch = rr >> 3;
#pragma unroll
        for (int i = 0; i < 2; i++) {
            int cc = c + i * 32;
            int rowi = c0 + cc;
            f16x8 o;
#pragma unroll
            for (int j = 0; j < 8; j++) o[j] = t[rr + j][cc];
            *(f16x8*)(dst + (size_t)rowi * R + r0 + (((ch ^ rowi) & 7) << 3)) = o;
        }
    }
}

// ---------------- router ----------------
__global__ __launch_bounds__(256) void router(const float* __restrict__ x,
                                              const float* __restrict__ gw,
                                              const float* __restrict__ gb,
                                              int* __restrict__ counts,
                                              int* __restrict__ list,
                                              float* __restrict__ wslot) {
    int wv = threadIdx.x >> 6;
    int lane = threadIdx.x & 63;
    int tok = blockIdx.x * 4 + wv;
    const float* xr = x + (size_t)tok * D_;
    float acc[E_];
#pragma unroll
    for (int e = 0; e < E_; e++) acc[e] = 0.f;
    for (int d = lane; d < D_; d += 64) {
        float v = xr[d];
        const float* g = gw + d * E_;
#pragma unroll
        for (int e = 0; e < E_; e++) acc[e] += v * g[e];
    }
#pragma unroll
    for (int e = 0; e < E_; e++) {
#pragma unroll
        for (int off = 32; off; off >>= 1) acc[e] += __shfl_xor(acc[e], off, 64);
    }
    if (lane == 0) {
        float v0 = -3.4e38f, v1 = -3.4e38f;
        int i0 = 0, i1 = 0;
#pragma unroll
        for (int e = 0; e < E_; e++) {
            float l = acc[e] + gb[e];
            if (l > v0) { v1 = v0; i1 = i0; v0 = l; i0 = e; }
            else if (l > v1) { v1 = l; i1 = e; }
        }
        float p1 = expf(v1 - v0);
        float s = 1.f + p1;
        int p0 = atomicAdd(&counts[i0], 1);
        list[i0 * N_TOK + p0] = tok * 2;
        int p1p = atomicAdd(&counts[i1], 1);
        list[i1 * N_TOK + p1p] = tok * 2 + 1;
        wslot[tok * 2] = 1.f / s;
        wslot[tok * 2 + 1] = p1 / s;
    }
}

// ---------------- prefix scan over 8 counts ----------------
__global__ void scan8(const int* __restrict__ counts, int* __restrict__ offs) {
    if (threadIdx.x == 0) {
        int s = 0;
#pragma unroll
        for (int e = 0; e < E_; e++) { offs[e] = s; s += counts[e]; }
        offs[E_] = s;
    }
}

// ---------------- pack A: gather token rows -> packed swizzled fp16 [8192][D] ----------------
__global__ __launch_bounds__(256) void pack_a(const float* __restrict__ x,
                                              const int* __restrict__ counts,
                                              const int* __restrict__ offs,
                                              const int* __restrict__ list,
                                              f16* __restrict__ xg) {
    int wv = threadIdx.x >> 6, lane = threadIdx.x & 63;
    int idx = blockIdx.x * 4 + wv;            // e*N_TOK + j
    int e = idx >> 12, j = idx & (N_TOK - 1);
    if (j >= counts[e]) return;
    int id = list[idx];
    int row = offs[e] + j;
    const float* xr = x + (size_t)(id >> 1) * D_;
    f16* dst = xg + (size_t)row * D_;
    int r7 = row & 7;
#pragma unroll
    for (int c = 0; c < 3; c++) {
        int h = lane * 4 + c * 256;
        float4 v = *(const float4*)(xr + h);
        f16 o[4] = {(f16)v.x, (f16)v.y, (f16)v.z, (f16)v.w};
        int hs = (h & ~0x3F) | ((((h >> 3) ^ r7) & 7) << 3) | (h & 7);
        *(float2*)(dst + hs) = *(const float2*)o;
    }
}

// ---------------- GEMM1: h = gelu(xg @ w1 + b1), 64x64, dbuf gld_lds ----------------
__global__ __launch_bounds__(256, 8) void gemm1(const f16* __restrict__ xg,
                                                const f16* __restrict__ w1t,
                                                const float* __restrict__ b1,
                                                const int* __restrict__ counts,
                                                const int* __restrict__ offs,
                                                f16* __restrict__ hbuf) {
    int e = blockIdx.z;
    int cnt = counts[e];
    int off = offs[e];
    int rb = blockIdx.y * BT;
    if (rb >= cnt) return;
    int cb = blockIdx.x * BT;

    __shared__ f16 lds[2][2 * BT * BK];   // per buffer: A halfs [0,4096), B [4096,8192)
    char* ldsb = (char*)&lds[0][0];

    int tid = threadIdx.x;
    int wv = tid >> 6, lane = tid & 63;
    int lr = lane >> 3, lc = lane & 7;

    int r0l = wv * 8 + lr;
    int r1l = 32 + wv * 8 + lr;
    int ag0 = off + rb + r0l; if (ag0 > 8191) ag0 = 8191;
    int ag1 = off + rb + r1l; if (ag1 > 8191) ag1 = 8191;
    const f16* ap0 = xg + (size_t)ag0 * D_ + lc * 8;
    const f16* ap1 = xg + (size_t)ag1 * D_ + lc * 8;
    const f16* wb = w1t + (size_t)e * H_ * D_;
    const f16* bp0 = wb + (size_t)(cb + r0l) * D_ + lc * 8;
    const f16* bp1 = wb + (size_t)(cb + r1l) * D_ + lc * 8;
    f16* la0 = &lds[0][0] + wv * 512;
    f16* la1 = &lds[0][0] + 2048 + wv * 512;
    f16* lb0 = &lds[0][0] + 4096 + wv * 512;
    f16* lb1 = &lds[0][0] + 6144 + wv * 512;

    int wr = (wv >> 1) * 32, wc = (wv & 1) * 32;
    int fr = lane & 15, qh = lane >> 4;
    int koff = (off + rb) & 7;

    int roA[2][2], roB[2][2];
#pragma unroll
    for (int m = 0; m < 2; m++)
#pragma unroll
        for (int ks = 0; ks < 2; ks++) {
            int row = wr + m * 16 + fr;
            roA[m][ks] = row * 128 + ((((ks * 4 + qh) ^ (koff + row)) & 7) << 4);
            int rwb = wc + m * 16 + fr;
            roB[m][ks] = 8192 + rwb * 128 + ((((ks * 4 + qh) ^ rwb) & 7) << 4);
        }

    f32x4 acc[2][2] = {};
    const int NT = D_ / BK;  // 12

    // prologue: stage tile 0 into buffer 0
    gld16(ap0, la0); gld16(ap1, la1); gld16(bp0, lb0); gld16(bp1, lb1);
    asm volatile("s_waitcnt vmcnt(0)" ::: "memory");
    __syncthreads();

#pragma unroll 1
    for (int t = 0; t < NT; ++t) {
        int nb = (t + 1) & 1;            // buffer being staged
        int bo = (t & 1) << 14;          // byte offset of compute buffer
        if (t + 1 < NT) {
            int kk = (t + 1) * BK;
            int ho = nb << 13;           // half offset of stage buffer (8192 halfs)
            gld16(ap0 + kk, la0 + ho);
            gld16(ap1 + kk, la1 + ho);
            gld16(bp0 + kk, lb0 + ho);
            gld16(bp1 + kk, lb1 + ho);
        }
#pragma unroll
        for (int ks = 0; ks < 2; ks++) {
            f16x8 a0 = *(const f16x8*)(ldsb + bo + roA[0][ks]);
            f16x8 a1 = *(const f16x8*)(ldsb + bo + roA[1][ks]);
            f16x8 b0 = *(const f16x8*)(ldsb + bo + roB[0][ks]);
            f16x8 b1v = *(const f16x8*)(ldsb + bo + roB[1][ks]);
            acc[0][0] = __builtin_amdgcn_mfma_f32_16x16x32_f16(a0, b0, acc[0][0], 0, 0, 0);
            acc[0][1] = __builtin_amdgcn_mfma_f32_16x16x32_f16(a0, b1v, acc[0][1], 0, 0, 0);
            acc[1][0] = __builtin_amdgcn_mfma_f32_16x16x32_f16(a1, b0, acc[1][0], 0, 0, 0);
            acc[1][1] = __builtin_amdgcn_mfma_f32_16x16x32_f16(a1, b1v, acc[1][1], 0, 0, 0);
        }
        asm volatile("s_waitcnt vmcnt(0)" ::: "memory");
        __syncthreads();
    }

#pragma unroll
    for (int n = 0; n < 2; n++) {
        int colg = cb + wc + n * 16 + fr;
        float bias = b1[e * H_ + colg];
#pragma unroll
        for (int m = 0; m < 2; m++) {
#pragma unroll
            for (int r = 0; r < 4; r++) {
                int j = rb + wr + m * 16 + qh * 4 + r;
                if (j < cnt) {
                    float v = acc[m][n][r] + bias;
                    v = 0.5f * v * (1.f + erff(v * 0.70710678f));
                    int row = off + j;
                    int hs = (colg & ~0x3F) | ((((colg >> 3) ^ row) & 7) << 3) | (colg & 7);
                    hbuf[(size_t)row * H_ + hs] = (f16)v;
                }
            }
        }
    }
}

// ---------------- GEMM2: y = (hbuf @ w2 + b2) * wslot, scatter-add ----------------
#define KSPLIT 2
#define KCH (H_ / KSPLIT)
__global__ __launch_bounds__(256, 8) void gemm2(const f16* __restrict__ hbuf,
                                                const f16* __restrict__ w2t,
                                                const float* __restrict__ b2,
                                                const int* __restrict__ counts,
                                                const int* __restrict__ offs,
                                                const int* __restrict__ list,
                                                const float* __restrict__ wslot,
                                                float* __restrict__ out) {
    int e = blockIdx.z;
    int cnt = counts[e];
    int off = offs[e];
    int rb = blockIdx.y * BT;
    if (rb >= cnt) return;
    int xk = blockIdx.x;                 // 0..23
    int cb = (xk % (D_ / BT)) * BT;
    int kz = xk / (D_ / BT);
    int k0 = kz * KCH;

    __shared__ f16 lds[2][2 * BT * BK];
    char* ldsb = (char*)&lds[0][0];

    int tid = threadIdx.x;
    int wv = tid >> 6, lane = tid & 63;
    int lr = lane >> 3, lc = lane & 7;

    int r0l = wv * 8 + lr;
    int r1l = 32 + wv * 8 + lr;
    int ag0 = off + rb + r0l; if (ag0 > 8191) ag0 = 8191;
    int ag1 = off + rb + r1l; if (ag1 > 8191) ag1 = 8191;
    const f16* ap0 = hbuf + (size_t)ag0 * H_ + k0 + lc * 8;
    const f16* ap1 = hbuf + (size_t)ag1 * H_ + k0 + lc * 8;
    const f16* wb = w2t + (size_t)e * D_ * H_;
    const f16* bp0 = wb + (size_t)(cb + r0l) * H_ + k0 + lc * 8;
    const f16* bp1 = wb + (size_t)(cb + r1l) * H_ + k0 + lc * 8;
    f16* la0 = &lds[0][0] + wv * 512;
    f16* la1 = &lds[0][0] + 2048 + wv * 512;
    f16* lb0 = &lds[0][0] + 4096 + wv * 512;
    f16* lb1 = &lds[0][0] + 6144 + wv * 512;

    int wr = (wv >> 1) * 32, wc = (wv & 1) * 32;
    int fr = lane & 15, qh = lane >> 4;
    int koff = (off + rb) & 7;

    int roA[2][2], roB[2][2];
#pragma unroll
    for (int m = 0; m < 2; m++)
#pragma unroll
        for (int ks = 0; ks < 2; ks++) {
            int row = wr + m * 16 + fr;
            roA[m][ks] = row * 128 + ((((ks * 4 + qh) ^ (koff + row)) & 7) << 4);
            int rwb = wc + m * 16 + fr;
            roB[m][ks] = 8192 + rwb * 128 + ((((ks * 4 + qh) ^ rwb) & 7) << 4);
        }

    f32x4 acc[2][2] = {};
    const int NT = KCH / BK;  // 24

    gld16(ap0, la0); gld16(ap1, la1); gld16(bp0, lb0); gld16(bp1, lb1);
    asm volatile("s_waitcnt vmcnt(0)" ::: "memory");
    __syncthreads();

#pragma unroll 1
    for (int t = 0; t < NT; ++t) {
        int nb = (t + 1) & 1;
        int bo = (t & 1) << 14;
        if (t + 1 < NT) {
            int kk = (t + 1) * BK;
            int ho = nb << 13;
            gld16(ap0 + kk, la0 + ho);
            gld16(ap1 + kk, la1 + ho);
            gld16(bp0 + kk, lb0 + ho);
            gld16(bp1 + kk, lb1 + ho);
        }
#pragma unroll
        for (int ks = 0; ks < 2; ks++) {
            f16x8 a0 = *(const f16x8*)(ldsb + bo + roA[0][ks]);
            f16x8 a1 = *(const f16x8*)(ldsb + bo + roA[1][ks]);
            f16x8 b0 = *(const f16x8*)(ldsb + bo + roB[0][ks]);
            f16x8 b1v = *(const f16x8*)(ldsb + bo + roB[1][ks]);
            acc[0][0] = __builtin_amdgcn_mfma_f32_16x16x32_f16(a0, b0, acc[0][0], 0, 0, 0);
            acc[0][1] = __builtin_amdgcn_mfma_f32_16x16x32_f16(a0, b1v, acc[0][1], 0, 0, 0);
            acc[1][0] = __builtin_amdgcn_mfma_f32_16x16x32_f16(a1, b0, acc[1][0], 0, 0, 0);
            acc[1][1] = __builtin_amdgcn_mfma_f32_16x16x32_f16(a1, b1v, acc[1][1], 0, 0, 0);
        }
        asm volatile("s_waitcnt vmcnt(0)" ::: "memory");
        __syncthreads();
    }

#pragma unroll
    for (int n = 0; n < 2; n++) {
        int colg = cb + wc + n * 16 + fr;
        float bias = (kz == 0) ? b2[e * D_ + colg] : 0.f;
#pragma unroll
        for (int m = 0; m < 2; m++) {
#pragma unroll
            for (int r = 0; r < 4; r++) {
                int j = rb + wr + m * 16 + qh * 4 + r;
                if (j < cnt) {
                    int id = list[e * N_TOK + j];
                    float w = wslot[id];
                    float v = (acc[m][n][r] + bias) * w;
                    atomicAdd(&out[(size_t)(id >> 1) * D_ + colg], v);
                }
            }
        }
    }
}

extern "C" void kernel_launch(void* const* d_in, const int* in_sizes, int n_in,
                              void* d_out, int out_size, void* d_ws, size_t ws_size,
                              hipStream_t stream) {
    const float* x = (const float*)d_in[0];
    const float* gate_w = (const float*)d_in[1];
    const float* gate_b = (const float*)d_in[2];
    const float* w1 = (const float*)d_in[3];
    const float* b1 = (const float*)d_in[4];
    const float* w2 = (const float*)d_in[5];
    const float* b2 = (const float*)d_in[6];
    float* out = (float*)d_out;

    char* ws = (char*)d_ws;
    int* counts = (int*)ws;                           // 32 B
    int* offs = (int*)(ws + 256);                     // 36 B
    int* list = (int*)(ws + 1024);                    // 131072 B
    float* wslot = (float*)(ws + 132096);             // 32768 B
    f16* xg = (f16*)(ws + 196608);                    // 12582912 B
    f16* w1t = (f16*)(ws + 12779520);                 // 37748736 B
    f16* w2t = (f16*)(ws + 50528256);                 // 37748736 B
    f16* hbuf = (f16*)(ws + 88276992);                // 50331648 B

    hipMemsetAsync(counts, 0, 256, stream);
    hipMemsetAsync(out, 0, (size_t)out_size * sizeof(float), stream);

    router<<<1024, 256, 0, stream>>>(x, gate_w, gate_b, counts, list, wslot);
    scan8<<<1, 64, 0, stream>>>(counts, offs);
    pack_a<<<E_ * N_TOK / 4, 256, 0, stream>>>(x, counts, offs, list, xg);
    cvt_w_t<<<dim3(H_ / 64, D_ / 64, E_), 256, 0, stream>>>(w1, w1t, D_, H_);
    cvt_w_t<<<dim3(D_ / 64, H_ / 64, E_), 256, 0, stream>>>(w2, w2t, H_, D_);
    gemm1<<<dim3(H_ / BT, N_TOK / BT, E_), 256, 0, stream>>>(xg, w1t, b1, counts, offs, hbuf);
    gemm2<<<dim3((D_ / BT) * KSPLIT, N_TOK / BT, E_), 256, 0, stream>>>(hbuf, w2t, b2, counts, offs, list, wslot, out);
}

// Round 11
// 327.511 us; speedup vs baseline: 1.1417x; 1.1277x over previous
//
#include <hip/hip_runtime.h>
#include <hip/hip_bf16.h>

#define D_ 768
#define E_ 8
#define H_ 3072
#define N_TOK 4096
#define BT 64
#define BK 64

typedef _Float16 f16;
typedef f16 f16x8 __attribute__((ext_vector_type(8)));
typedef float f32x4 __attribute__((ext_vector_type(4)));

__device__ __forceinline__ void gld16(const f16* g, f16* l) {
    __builtin_amdgcn_global_load_lds(
        (const __attribute__((address_space(1))) unsigned int*)g,
        (__attribute__((address_space(3))) unsigned int*)l, 16, 0, 0);
}

// ---------------- weight convert + transpose + swizzle: fp32 [R][C] -> fp16 [C][R] ----------------
#define TP 66
__global__ __launch_bounds__(256) void cvt_w_t(const float* __restrict__ in,
                                               f16* __restrict__ outp,
                                               int R, int C) {
    __shared__ f16 t[64][TP];
    const float* src = in + (size_t)blockIdx.z * R * C;
    f16* dst = outp + (size_t)blockIdx.z * R * C;
    int r0 = blockIdx.y * 64, c0 = blockIdx.x * 64;
    int tid = threadIdx.x;
    {
        int r = tid >> 4;
        int c = (tid & 15) * 4;
#pragma unroll
        for (int i = 0; i < 4; i++) {
            float4 v = *(const float4*)(src + (size_t)(r0 + r + i * 16) * C + (c0 + c));
            t[r + i * 16][c] = (f16)v.x;
            t[r + i * 16][c + 1] = (f16)v.y;
            t[r + i * 16][c + 2] = (f16)v.z;
            t[r + i * 16][c + 3] = (f16)v.w;
        }
    }
    __syncthreads();
    {
        int c = tid >> 3;
        int rr = (tid & 7) * 8;
        int ch = rr >> 3;
#pragma unroll
        for (int i = 0; i < 2; i++) {
            int cc = c + i * 32;
            int rowi = c0 + cc;
            f16x8 o;
#pragma unroll
            for (int j = 0; j < 8; j++) o[j] = t[rr + j][cc];
            *(f16x8*)(dst + (size_t)rowi * R + r0 + (((ch ^ rowi) & 7) << 3)) = o;
        }
    }
}

// ---------------- router ----------------
__global__ __launch_bounds__(256) void router(const float* __restrict__ x,
                                              const float* __restrict__ gw,
                                              const float* __restrict__ gb,
                                              int* __restrict__ counts,
                                              int* __restrict__ list,
                                              float* __restrict__ wslot) {
    int wv = threadIdx.x >> 6;
    int lane = threadIdx.x & 63;
    int tok = blockIdx.x * 4 + wv;
    const float* xr = x + (size_t)tok * D_;
    float acc[E_];
#pragma unroll
    for (int e = 0; e < E_; e++) acc[e] = 0.f;
    for (int d = lane; d < D_; d += 64) {
        float v = xr[d];
        const float* g = gw + d * E_;
#pragma unroll
        for (int e = 0; e < E_; e++) acc[e] += v * g[e];
    }
#pragma unroll
    for (int e = 0; e < E_; e++) {
#pragma unroll
        for (int off = 32; off; off >>= 1) acc[e] += __shfl_xor(acc[e], off, 64);
    }
    if (lane == 0) {
        float v0 = -3.4e38f, v1 = -3.4e38f;
        int i0 = 0, i1 = 0;
#pragma unroll
        for (int e = 0; e < E_; e++) {
            float l = acc[e] + gb[e];
            if (l > v0) { v1 = v0; i1 = i0; v0 = l; i0 = e; }
            else if (l > v1) { v1 = l; i1 = e; }
        }
        float p1 = expf(v1 - v0);
        float s = 1.f + p1;
        int p0 = atomicAdd(&counts[i0], 1);
        list[i0 * N_TOK + p0] = tok * 2;
        int p1p = atomicAdd(&counts[i1], 1);
        list[i1 * N_TOK + p1p] = tok * 2 + 1;
        wslot[tok * 2] = 1.f / s;
        wslot[tok * 2 + 1] = p1 / s;
    }
}

// ---------------- prefix scan over 8 counts ----------------
__global__ void scan8(const int* __restrict__ counts, int* __restrict__ offs) {
    if (threadIdx.x == 0) {
        int s = 0;
#pragma unroll
        for (int e = 0; e < E_; e++) { offs[e] = s; s += counts[e]; }
        offs[E_] = s;
    }
}

// ---------------- pack A: gather token rows -> packed swizzled fp16 [8192][D] ----------------
__global__ __launch_bounds__(256) void pack_a(const float* __restrict__ x,
                                              const int* __restrict__ counts,
                                              const int* __restrict__ offs,
                                              const int* __restrict__ list,
                                              f16* __restrict__ xg) {
    int wv = threadIdx.x >> 6, lane = threadIdx.x & 63;
    int idx = blockIdx.x * 4 + wv;            // e*N_TOK + j
    int e = idx >> 12, j = idx & (N_TOK - 1);
    if (j >= counts[e]) return;
    int id = list[idx];
    int row = offs[e] + j;
    const float* xr = x + (size_t)(id >> 1) * D_;
    f16* dst = xg + (size_t)row * D_;
    int r7 = row & 7;
#pragma unroll
    for (int c = 0; c < 3; c++) {
        int h = lane * 4 + c * 256;
        float4 v = *(const float4*)(xr + h);
        f16 o[4] = {(f16)v.x, (f16)v.y, (f16)v.z, (f16)v.w};
        int hs = (h & ~0x3F) | ((((h >> 3) ^ r7) & 7) << 3) | (h & 7);
        *(float2*)(dst + hs) = *(const float2*)o;
    }
}

// ---------------- GEMM1: h = gelu(xg @ w1 + b1), 64x64 tiles, gld_lds, XCD-pinned ----------------
#define NXB1 (H_ / BT)   // 48
__global__ __launch_bounds__(256, 8) void gemm1(const f16* __restrict__ xg,
                                                const f16* __restrict__ w1t,
                                                const float* __restrict__ b1,
                                                const int* __restrict__ counts,
                                                const int* __restrict__ offs,
                                                f16* __restrict__ hbuf) {
    int bid = blockIdx.x;
    int e = bid & 7;                 // expert -> XCD (round-robin bid%8)
    int r = bid >> 3;
    int xb = r % NXB1;               // fastest within expert: shares A panel
    int yb = r / NXB1;
    int cnt = counts[e];
    int off = offs[e];
    int rb = yb * BT;
    if (rb >= cnt) return;
    int cb = xb * BT;

    __shared__ f16 lds[2 * BT * BK];   // A halfs [0,4096), B halfs [4096,8192)
    char* ldsb = (char*)lds;

    int tid = threadIdx.x;
    int wv = tid >> 6, lane = tid & 63;
    int lr = lane >> 3, lc = lane & 7;

    int r0l = wv * 8 + lr;             // rows 0..31
    int r1l = 32 + wv * 8 + lr;        // rows 32..63
    int ag0 = off + rb + r0l; if (ag0 > 8191) ag0 = 8191;
    int ag1 = off + rb + r1l; if (ag1 > 8191) ag1 = 8191;
    const f16* ap0 = xg + (size_t)ag0 * D_ + lc * 8;
    const f16* ap1 = xg + (size_t)ag1 * D_ + lc * 8;
    const f16* wb = w1t + (size_t)e * H_ * D_;
    const f16* bp0 = wb + (size_t)(cb + r0l) * D_ + lc * 8;
    const f16* bp1 = wb + (size_t)(cb + r1l) * D_ + lc * 8;
    f16* la0 = lds + wv * 512;
    f16* la1 = lds + 2048 + wv * 512;
    f16* lb0 = lds + 4096 + wv * 512;
    f16* lb1 = lds + 6144 + wv * 512;

    int wr = (wv >> 1) * 32, wc = (wv & 1) * 32;
    int fr = lane & 15, qh = lane >> 4;
    int koff = (off + rb) & 7;

    int roA[2][2], roB[2][2];
#pragma unroll
    for (int m = 0; m < 2; m++)
#pragma unroll
        for (int ks = 0; ks < 2; ks++) {
            int row = wr + m * 16 + fr;
            roA[m][ks] = row * 128 + ((((ks * 4 + qh) ^ (koff + row)) & 7) << 4);
            int rwb = wc + m * 16 + fr;
            roB[m][ks] = 8192 + rwb * 128 + ((((ks * 4 + qh) ^ rwb) & 7) << 4);
        }

    f32x4 acc[2][2] = {};
    const int NT = D_ / BK;  // 12
#pragma unroll 1
    for (int t = 0; t < NT; ++t) {
        int kk = t * BK;
        gld16(ap0 + kk, la0);
        gld16(ap1 + kk, la1);
        gld16(bp0 + kk, lb0);
        gld16(bp1 + kk, lb1);
        __syncthreads();
#pragma unroll
        for (int ks = 0; ks < 2; ks++) {
            f16x8 a0 = *(const f16x8*)(ldsb + roA[0][ks]);
            f16x8 a1 = *(const f16x8*)(ldsb + roA[1][ks]);
            f16x8 b0 = *(const f16x8*)(ldsb + roB[0][ks]);
            f16x8 b1v = *(const f16x8*)(ldsb + roB[1][ks]);
            acc[0][0] = __builtin_amdgcn_mfma_f32_16x16x32_f16(a0, b0, acc[0][0], 0, 0, 0);
            acc[0][1] = __builtin_amdgcn_mfma_f32_16x16x32_f16(a0, b1v, acc[0][1], 0, 0, 0);
            acc[1][0] = __builtin_amdgcn_mfma_f32_16x16x32_f16(a1, b0, acc[1][0], 0, 0, 0);
            acc[1][1] = __builtin_amdgcn_mfma_f32_16x16x32_f16(a1, b1v, acc[1][1], 0, 0, 0);
        }
        __syncthreads();
    }

#pragma unroll
    for (int n = 0; n < 2; n++) {
        int colg = cb + wc + n * 16 + fr;
        float bias = b1[e * H_ + colg];
#pragma unroll
        for (int m = 0; m < 2; m++) {
#pragma unroll
            for (int r2 = 0; r2 < 4; r2++) {
                int j = rb + wr + m * 16 + qh * 4 + r2;
                if (j < cnt) {
                    float v = acc[m][n][r2] + bias;
                    v = 0.5f * v * (1.f + erff(v * 0.70710678f));
                    int row = off + j;
                    int hs = (colg & ~0x3F) | ((((colg >> 3) ^ row) & 7) << 3) | (colg & 7);
                    hbuf[(size_t)row * H_ + hs] = (f16)v;
                }
            }
        }
    }
}

// ---------------- GEMM2: y = (hbuf @ w2 + b2) * wslot, scatter-add, XCD-pinned ----------------
#define KSPLIT 2
#define KCH (H_ / KSPLIT)
#define NXB2 ((D_ / BT) * KSPLIT)   // 24
__global__ __launch_bounds__(256, 8) void gemm2(const f16* __restrict__ hbuf,
                                                const f16* __restrict__ w2t,
                                                const float* __restrict__ b2,
                                                const int* __restrict__ counts,
                                                const int* __restrict__ offs,
                                                const int* __restrict__ list,
                                                const float* __restrict__ wslot,
                                                float* __restrict__ out) {
    int bid = blockIdx.x;
    int e = bid & 7;                 // expert -> XCD
    int r = bid >> 3;
    int xk = r % NXB2;               // fastest within expert
    int yb = r / NXB2;
    int cnt = counts[e];
    int off = offs[e];
    int rb = yb * BT;
    if (rb >= cnt) return;
    int cb = (xk % (D_ / BT)) * BT;
    int kz = xk / (D_ / BT);
    int k0 = kz * KCH;

    __shared__ f16 lds[2 * BT * BK];
    char* ldsb = (char*)lds;

    int tid = threadIdx.x;
    int wv = tid >> 6, lane = tid & 63;
    int lr = lane >> 3, lc = lane & 7;

    int r0l = wv * 8 + lr;
    int r1l = 32 + wv * 8 + lr;
    int ag0 = off + rb + r0l; if (ag0 > 8191) ag0 = 8191;
    int ag1 = off + rb + r1l; if (ag1 > 8191) ag1 = 8191;
    const f16* ap0 = hbuf + (size_t)ag0 * H_ + k0 + lc * 8;
    const f16* ap1 = hbuf + (size_t)ag1 * H_ + k0 + lc * 8;
    const f16* wb = w2t + (size_t)e * D_ * H_;
    const f16* bp0 = wb + (size_t)(cb + r0l) * H_ + k0 + lc * 8;
    const f16* bp1 = wb + (size_t)(cb + r1l) * H_ + k0 + lc * 8;
    f16* la0 = lds + wv * 512;
    f16* la1 = lds + 2048 + wv * 512;
    f16* lb0 = lds + 4096 + wv * 512;
    f16* lb1 = lds + 6144 + wv * 512;

    int wr = (wv >> 1) * 32, wc = (wv & 1) * 32;
    int fr = lane & 15, qh = lane >> 4;
    int koff = (off + rb) & 7;

    int roA[2][2], roB[2][2];
#pragma unroll
    for (int m = 0; m < 2; m++)
#pragma unroll
        for (int ks = 0; ks < 2; ks++) {
            int row = wr + m * 16 + fr;
            roA[m][ks] = row * 128 + ((((ks * 4 + qh) ^ (koff + row)) & 7) << 4);
            int rwb = wc + m * 16 + fr;
            roB[m][ks] = 8192 + rwb * 128 + ((((ks * 4 + qh) ^ rwb) & 7) << 4);
        }

    f32x4 acc[2][2] = {};
    const int NT = KCH / BK;  // 24
#pragma unroll 1
    for (int t = 0; t < NT; ++t) {
        int kk = t * BK;
        gld16(ap0 + kk, la0);
        gld16(ap1 + kk, la1);
        gld16(bp0 + kk, lb0);
        gld16(bp1 + kk, lb1);
        __syncthreads();
#pragma unroll
        for (int ks = 0; ks < 2; ks++) {
            f16x8 a0 = *(const f16x8*)(ldsb + roA[0][ks]);
            f16x8 a1 = *(const f16x8*)(ldsb + roA[1][ks]);
            f16x8 b0 = *(const f16x8*)(ldsb + roB[0][ks]);
            f16x8 b1v = *(const f16x8*)(ldsb + roB[1][ks]);
            acc[0][0] = __builtin_amdgcn_mfma_f32_16x16x32_f16(a0, b0, acc[0][0], 0, 0, 0);
            acc[0][1] = __builtin_amdgcn_mfma_f32_16x16x32_f16(a0, b1v, acc[0][1], 0, 0, 0);
            acc[1][0] = __builtin_amdgcn_mfma_f32_16x16x32_f16(a1, b0, acc[1][0], 0, 0, 0);
            acc[1][1] = __builtin_amdgcn_mfma_f32_16x16x32_f16(a1, b1v, acc[1][1], 0, 0, 0);
        }
        __syncthreads();
    }

#pragma unroll
    for (int n = 0; n < 2; n++) {
        int colg = cb + wc + n * 16 + fr;
        float bias = (kz == 0) ? b2[e * D_ + colg] : 0.f;
#pragma unroll
        for (int m = 0; m < 2; m++) {
#pragma unroll
            for (int r2 = 0; r2 < 4; r2++) {
                int j = rb + wr + m * 16 + qh * 4 + r2;
                if (j < cnt) {
                    int id = list[e * N_TOK + j];
                    float w = wslot[id];
                    float v = (acc[m][n][r2] + bias) * w;
                    atomicAdd(&out[(size_t)(id >> 1) * D_ + colg], v);
                }
            }
        }
    }
}

extern "C" void kernel_launch(void* const* d_in, const int* in_sizes, int n_in,
                              void* d_out, int out_size, void* d_ws, size_t ws_size,
                              hipStream_t stream) {
    const float* x = (const float*)d_in[0];
    const float* gate_w = (const float*)d_in[1];
    const float* gate_b = (const float*)d_in[2];
    const float* w1 = (const float*)d_in[3];
    const float* b1 = (const float*)d_in[4];
    const float* w2 = (const float*)d_in[5];
    const float* b2 = (const float*)d_in[6];
    float* out = (float*)d_out;

    char* ws = (char*)d_ws;
    int* counts = (int*)ws;                           // 32 B
    int* offs = (int*)(ws + 256);                     // 36 B
    int* list = (int*)(ws + 1024);                    // 131072 B
    float* wslot = (float*)(ws + 132096);             // 32768 B
    f16* xg = (f16*)(ws + 196608);                    // 12582912 B
    f16* w1t = (f16*)(ws + 12779520);                 // 37748736 B
    f16* w2t = (f16*)(ws + 50528256);                 // 37748736 B
    f16* hbuf = (f16*)(ws + 88276992);                // 50331648 B

    hipMemsetAsync(counts, 0, 256, stream);
    hipMemsetAsync(out, 0, (size_t)out_size * sizeof(float), stream);

    router<<<1024, 256, 0, stream>>>(x, gate_w, gate_b, counts, list, wslot);
    scan8<<<1, 64, 0, stream>>>(counts, offs);
    pack_a<<<E_ * N_TOK / 4, 256, 0, stream>>>(x, counts, offs, list, xg);
    cvt_w_t<<<dim3(H_ / 64, D_ / 64, E_), 256, 0, stream>>>(w1, w1t, D_, H_);
    cvt_w_t<<<dim3(D_ / 64, H_ / 64, E_), 256, 0, stream>>>(w2, w2t, H_, D_);
    gemm1<<<E_ * NXB1 * (N_TOK / BT), 256, 0, stream>>>(xg, w1t, b1, counts, offs, hbuf);
    gemm2<<<E_ * NXB2 * (N_TOK / BT), 256, 0, stream>>>(hbuf, w2t, b2, counts, offs, list, wslot, out);
}

// Round 12
// 263.332 us; speedup vs baseline: 1.4200x; 1.2437x over previous
//
#include <hip/hip_runtime.h>
#include <hip/hip_bf16.h>

#define D_ 768
#define E_ 8
#define H_ 3072
#define N_TOK 4096
#define BT 64
#define BK 64

typedef _Float16 f16;
typedef f16 f16x8 __attribute__((ext_vector_type(8)));
typedef float f32x4 __attribute__((ext_vector_type(4)));

__device__ __forceinline__ void gld16(const f16* g, f16* l) {
    __builtin_amdgcn_global_load_lds(
        (const __attribute__((address_space(1))) unsigned int*)g,
        (__attribute__((address_space(3))) unsigned int*)l, 16, 0, 0);
}

// ---------------- weight convert + transpose + swizzle: fp32 [R][C] -> fp16 [C][R] ----------------
#define TP 66
__global__ __launch_bounds__(256) void cvt_w_t(const float* __restrict__ in,
                                               f16* __restrict__ outp,
                                               int R, int C) {
    __shared__ f16 t[64][TP];
    const float* src = in + (size_t)blockIdx.z * R * C;
    f16* dst = outp + (size_t)blockIdx.z * R * C;
    int r0 = blockIdx.y * 64, c0 = blockIdx.x * 64;
    int tid = threadIdx.x;
    {
        int r = tid >> 4;
        int c = (tid & 15) * 4;
#pragma unroll
        for (int i = 0; i < 4; i++) {
            float4 v = *(const float4*)(src + (size_t)(r0 + r + i * 16) * C + (c0 + c));
            t[r + i * 16][c] = (f16)v.x;
            t[r + i * 16][c + 1] = (f16)v.y;
            t[r + i * 16][c + 2] = (f16)v.z;
            t[r + i * 16][c + 3] = (f16)v.w;
        }
    }
    __syncthreads();
    {
        int c = tid >> 3;
        int rr = (tid & 7) * 8;
        int ch = rr >> 3;
#pragma unroll
        for (int i = 0; i < 2; i++) {
            int cc = c + i * 32;
            int rowi = c0 + cc;
            f16x8 o;
#pragma unroll
            for (int j = 0; j < 8; j++) o[j] = t[rr + j][cc];
            *(f16x8*)(dst + (size_t)rowi * R + r0 + (((ch ^ rowi) & 7) << 3)) = o;
        }
    }
}

// ---------------- router v2: coalesced GEMV + LDS-aggregated atomics ----------------
// 64 blocks x 1024 threads (16 waves); 64 tokens per block (4 per wave).
// lane = (stripe s = lane>>3, expert e = lane&7); gw read gw[j*64+lane] coalesced.
__global__ __launch_bounds__(1024) void router(const float* __restrict__ x,
                                               const float* __restrict__ gw,
                                               const float* __restrict__ gb,
                                               int* __restrict__ counts,
                                               int* __restrict__ list,
                                               float* __restrict__ wslot) {
    __shared__ int lcount[E_];
    __shared__ int lbase[E_];
    __shared__ int te0[64], te1[64], ts0[64], ts1[64];
    __shared__ float tw0[64], tw1[64];

    int tid = threadIdx.x;
    int wv = tid >> 6, lane = tid & 63;
    int s = lane >> 3, eL = lane & 7;
    if (tid < E_) lcount[tid] = 0;
    __syncthreads();

    float biasL = gb[eL];

#pragma unroll 1
    for (int i = 0; i < 4; i++) {
        int lt = wv * 4 + i;                       // local token 0..63
        int tok = blockIdx.x * 64 + lt;
        const float* xr = x + (size_t)tok * D_;
        float a = 0.f;
        const float* gwl = gw + lane;
#pragma unroll 8
        for (int j = 0; j < 96; j++)
            a = fmaf(xr[j * 8 + s], gwl[j * 64], a);
        a += __shfl_xor(a, 8, 64);
        a += __shfl_xor(a, 16, 64);
        a += __shfl_xor(a, 32, 64);
        float lg = a + biasL;                      // every lane: logit for its e-class
        float le[8];
#pragma unroll
        for (int q = 0; q < 8; q++) le[q] = __shfl(lg, q, 64);
        float v0 = -3.4e38f, v1 = -3.4e38f;
        int i0 = 0, i1 = 0;
#pragma unroll
        for (int q = 0; q < 8; q++) {
            float l = le[q];
            if (l > v0) { v1 = v0; i1 = i0; v0 = l; i0 = q; }
            else if (l > v1) { v1 = l; i1 = q; }
        }
        if (lane == 0) {
            float p1 = expf(v1 - v0);
            float ssum = 1.f + p1;
            int s0 = atomicAdd(&lcount[i0], 1);
            int s1 = atomicAdd(&lcount[i1], 1);
            te0[lt] = i0; ts0[lt] = s0; tw0[lt] = 1.f / ssum;
            te1[lt] = i1; ts1[lt] = s1; tw1[lt] = p1 / ssum;
        }
    }
    __syncthreads();
    if (tid < E_) lbase[tid] = atomicAdd(&counts[tid], lcount[tid]);
    __syncthreads();
    if (tid < 64) {
        int tok = blockIdx.x * 64 + tid;
        int e0 = te0[tid], e1 = te1[tid];
        list[e0 * N_TOK + lbase[e0] + ts0[tid]] = tok * 2;
        list[e1 * N_TOK + lbase[e1] + ts1[tid]] = tok * 2 + 1;
        wslot[tok * 2] = tw0[tid];
        wslot[tok * 2 + 1] = tw1[tid];
    }
}

// ---------------- prefix scan over 8 counts ----------------
__global__ void scan8(const int* __restrict__ counts, int* __restrict__ offs) {
    if (threadIdx.x == 0) {
        int s = 0;
#pragma unroll
        for (int e = 0; e < E_; e++) { offs[e] = s; s += counts[e]; }
        offs[E_] = s;
    }
}

// ---------------- pack A: gather token rows -> packed swizzled fp16 [8192][D] ----------------
__global__ __launch_bounds__(256) void pack_a(const float* __restrict__ x,
                                              const int* __restrict__ counts,
                                              const int* __restrict__ offs,
                                              const int* __restrict__ list,
                                              f16* __restrict__ xg) {
    int wv = threadIdx.x >> 6, lane = threadIdx.x & 63;
    int idx = blockIdx.x * 4 + wv;            // e*N_TOK + j
    int e = idx >> 12, j = idx & (N_TOK - 1);
    if (j >= counts[e]) return;
    int id = list[idx];
    int row = offs[e] + j;
    const float* xr = x + (size_t)(id >> 1) * D_;
    f16* dst = xg + (size_t)row * D_;
    int r7 = row & 7;
#pragma unroll
    for (int c = 0; c < 3; c++) {
        int h = lane * 4 + c * 256;
        float4 v = *(const float4*)(xr + h);
        f16 o[4] = {(f16)v.x, (f16)v.y, (f16)v.z, (f16)v.w};
        int hs = (h & ~0x3F) | ((((h >> 3) ^ r7) & 7) << 3) | (h & 7);
        *(float2*)(dst + hs) = *(const float2*)o;
    }
}

// ---------------- GEMM1: h = gelu(xg @ w1 + b1), 64x64 tiles, gld_lds, XCD-pinned ----------------
#define NXB1 (H_ / BT)   // 48
__global__ __launch_bounds__(256, 8) void gemm1(const f16* __restrict__ xg,
                                                const f16* __restrict__ w1t,
                                                const float* __restrict__ b1,
                                                const int* __restrict__ counts,
                                                const int* __restrict__ offs,
                                                f16* __restrict__ hbuf) {
    int bid = blockIdx.x;
    int e = bid & 7;                 // expert -> XCD (round-robin bid%8)
    int r = bid >> 3;
    int xb = r % NXB1;               // fastest within expert: shares A panel
    int yb = r / NXB1;
    int cnt = counts[e];
    int off = offs[e];
    int rb = yb * BT;
    if (rb >= cnt) return;
    int cb = xb * BT;

    __shared__ f16 lds[2 * BT * BK];   // A halfs [0,4096), B halfs [4096,8192)
    char* ldsb = (char*)lds;

    int tid = threadIdx.x;
    int wv = tid >> 6, lane = tid & 63;
    int lr = lane >> 3, lc = lane & 7;

    int r0l = wv * 8 + lr;             // rows 0..31
    int r1l = 32 + wv * 8 + lr;        // rows 32..63
    int ag0 = off + rb + r0l; if (ag0 > 8191) ag0 = 8191;
    int ag1 = off + rb + r1l; if (ag1 > 8191) ag1 = 8191;
    const f16* ap0 = xg + (size_t)ag0 * D_ + lc * 8;
    const f16* ap1 = xg + (size_t)ag1 * D_ + lc * 8;
    const f16* wb = w1t + (size_t)e * H_ * D_;
    const f16* bp0 = wb + (size_t)(cb + r0l) * D_ + lc * 8;
    const f16* bp1 = wb + (size_t)(cb + r1l) * D_ + lc * 8;
    f16* la0 = lds + wv * 512;
    f16* la1 = lds + 2048 + wv * 512;
    f16* lb0 = lds + 4096 + wv * 512;
    f16* lb1 = lds + 6144 + wv * 512;

    int wr = (wv >> 1) * 32, wc = (wv & 1) * 32;
    int fr = lane & 15, qh = lane >> 4;
    int koff = (off + rb) & 7;

    int roA[2][2], roB[2][2];
#pragma unroll
    for (int m = 0; m < 2; m++)
#pragma unroll
        for (int ks = 0; ks < 2; ks++) {
            int row = wr + m * 16 + fr;
            roA[m][ks] = row * 128 + ((((ks * 4 + qh) ^ (koff + row)) & 7) << 4);
            int rwb = wc + m * 16 + fr;
            roB[m][ks] = 8192 + rwb * 128 + ((((ks * 4 + qh) ^ rwb) & 7) << 4);
        }

    f32x4 acc[2][2] = {};
    const int NT = D_ / BK;  // 12
#pragma unroll 1
    for (int t = 0; t < NT; ++t) {
        int kk = t * BK;
        gld16(ap0 + kk, la0);
        gld16(ap1 + kk, la1);
        gld16(bp0 + kk, lb0);
        gld16(bp1 + kk, lb1);
        __syncthreads();
#pragma unroll
        for (int ks = 0; ks < 2; ks++) {
            f16x8 a0 = *(const f16x8*)(ldsb + roA[0][ks]);
            f16x8 a1 = *(const f16x8*)(ldsb + roA[1][ks]);
            f16x8 b0 = *(const f16x8*)(ldsb + roB[0][ks]);
            f16x8 b1v = *(const f16x8*)(ldsb + roB[1][ks]);
            acc[0][0] = __builtin_amdgcn_mfma_f32_16x16x32_f16(a0, b0, acc[0][0], 0, 0, 0);
            acc[0][1] = __builtin_amdgcn_mfma_f32_16x16x32_f16(a0, b1v, acc[0][1], 0, 0, 0);
            acc[1][0] = __builtin_amdgcn_mfma_f32_16x16x32_f16(a1, b0, acc[1][0], 0, 0, 0);
            acc[1][1] = __builtin_amdgcn_mfma_f32_16x16x32_f16(a1, b1v, acc[1][1], 0, 0, 0);
        }
        __syncthreads();
    }

#pragma unroll
    for (int n = 0; n < 2; n++) {
        int colg = cb + wc + n * 16 + fr;
        float bias = b1[e * H_ + colg];
#pragma unroll
        for (int m = 0; m < 2; m++) {
#pragma unroll
            for (int r2 = 0; r2 < 4; r2++) {
                int j = rb + wr + m * 16 + qh * 4 + r2;
                if (j < cnt) {
                    float v = acc[m][n][r2] + bias;
                    v = 0.5f * v * (1.f + erff(v * 0.70710678f));
                    int row = off + j;
                    int hs = (colg & ~0x3F) | ((((colg >> 3) ^ row) & 7) << 3) | (colg & 7);
                    hbuf[(size_t)row * H_ + hs] = (f16)v;
                }
            }
        }
    }
}

// ---------------- GEMM2: y = (hbuf @ w2 + b2) * wslot, scatter-add, XCD-pinned ----------------
#define KSPLIT 2
#define KCH (H_ / KSPLIT)
#define NXB2 ((D_ / BT) * KSPLIT)   // 24
__global__ __launch_bounds__(256, 8) void gemm2(const f16* __restrict__ hbuf,
                                                const f16* __restrict__ w2t,
                                                const float* __restrict__ b2,
                                                const int* __restrict__ counts,
                                                const int* __restrict__ offs,
                                                const int* __restrict__ list,
                                                const float* __restrict__ wslot,
                                                float* __restrict__ out) {
    int bid = blockIdx.x;
    int e = bid & 7;                 // expert -> XCD
    int r = bid >> 3;
    int xk = r % NXB2;               // fastest within expert
    int yb = r / NXB2;
    int cnt = counts[e];
    int off = offs[e];
    int rb = yb * BT;
    if (rb >= cnt) return;
    int cb = (xk % (D_ / BT)) * BT;
    int kz = xk / (D_ / BT);
    int k0 = kz * KCH;

    __shared__ f16 lds[2 * BT * BK];
    char* ldsb = (char*)lds;

    int tid = threadIdx.x;
    int wv = tid >> 6, lane = tid & 63;
    int lr = lane >> 3, lc = lane & 7;

    int r0l = wv * 8 + lr;
    int r1l = 32 + wv * 8 + lr;
    int ag0 = off + rb + r0l; if (ag0 > 8191) ag0 = 8191;
    int ag1 = off + rb + r1l; if (ag1 > 8191) ag1 = 8191;
    const f16* ap0 = hbuf + (size_t)ag0 * H_ + k0 + lc * 8;
    const f16* ap1 = hbuf + (size_t)ag1 * H_ + k0 + lc * 8;
    const f16* wb = w2t + (size_t)e * D_ * H_;
    const f16* bp0 = wb + (size_t)(cb + r0l) * H_ + k0 + lc * 8;
    const f16* bp1 = wb + (size_t)(cb + r1l) * H_ + k0 + lc * 8;
    f16* la0 = lds + wv * 512;
    f16* la1 = lds + 2048 + wv * 512;
    f16* lb0 = lds + 4096 + wv * 512;
    f16* lb1 = lds + 6144 + wv * 512;

    int wr = (wv >> 1) * 32, wc = (wv & 1) * 32;
    int fr = lane & 15, qh = lane >> 4;
    int koff = (off + rb) & 7;

    int roA[2][2], roB[2][2];
#pragma unroll
    for (int m = 0; m < 2; m++)
#pragma unroll
        for (int ks = 0; ks < 2; ks++) {
            int row = wr + m * 16 + fr;
            roA[m][ks] = row * 128 + ((((ks * 4 + qh) ^ (koff + row)) & 7) << 4);
            int rwb = wc + m * 16 + fr;
            roB[m][ks] = 8192 + rwb * 128 + ((((ks * 4 + qh) ^ rwb) & 7) << 4);
        }

    f32x4 acc[2][2] = {};
    const int NT = KCH / BK;  // 24
#pragma unroll 1
    for (int t = 0; t < NT; ++t) {
        int kk = t * BK;
        gld16(ap0 + kk, la0);
        gld16(ap1 + kk, la1);
        gld16(bp0 + kk, lb0);
        gld16(bp1 + kk, lb1);
        __syncthreads();
#pragma unroll
        for (int ks = 0; ks < 2; ks++) {
            f16x8 a0 = *(const f16x8*)(ldsb + roA[0][ks]);
            f16x8 a1 = *(const f16x8*)(ldsb + roA[1][ks]);
            f16x8 b0 = *(const f16x8*)(ldsb + roB[0][ks]);
            f16x8 b1v = *(const f16x8*)(ldsb + roB[1][ks]);
            acc[0][0] = __builtin_amdgcn_mfma_f32_16x16x32_f16(a0, b0, acc[0][0], 0, 0, 0);
            acc[0][1] = __builtin_amdgcn_mfma_f32_16x16x32_f16(a0, b1v, acc[0][1], 0, 0, 0);
            acc[1][0] = __builtin_amdgcn_mfma_f32_16x16x32_f16(a1, b0, acc[1][0], 0, 0, 0);
            acc[1][1] = __builtin_amdgcn_mfma_f32_16x16x32_f16(a1, b1v, acc[1][1], 0, 0, 0);
        }
        __syncthreads();
    }

#pragma unroll
    for (int n = 0; n < 2; n++) {
        int colg = cb + wc + n * 16 + fr;
        float bias = (kz == 0) ? b2[e * D_ + colg] : 0.f;
#pragma unroll
        for (int m = 0; m < 2; m++) {
#pragma unroll
            for (int r2 = 0; r2 < 4; r2++) {
                int j = rb + wr + m * 16 + qh * 4 + r2;
                if (j < cnt) {
                    int id = list[e * N_TOK + j];
                    float w = wslot[id];
                    float v = (acc[m][n][r2] + bias) * w;
                    atomicAdd(&out[(size_t)(id >> 1) * D_ + colg], v);
                }
            }
        }
    }
}

extern "C" void kernel_launch(void* const* d_in, const int* in_sizes, int n_in,
                              void* d_out, int out_size, void* d_ws, size_t ws_size,
                              hipStream_t stream) {
    const float* x = (const float*)d_in[0];
    const float* gate_w = (const float*)d_in[1];
    const float* gate_b = (const float*)d_in[2];
    const float* w1 = (const float*)d_in[3];
    const float* b1 = (const float*)d_in[4];
    const float* w2 = (const float*)d_in[5];
    const float* b2 = (const float*)d_in[6];
    float* out = (float*)d_out;

    char* ws = (char*)d_ws;
    int* counts = (int*)ws;                           // 32 B
    int* offs = (int*)(ws + 256);                     // 36 B
    int* list = (int*)(ws + 1024);                    // 131072 B
    float* wslot = (float*)(ws + 132096);             // 32768 B
    f16* xg = (f16*)(ws + 196608);                    // 12582912 B
    f16* w1t = (f16*)(ws + 12779520);                 // 37748736 B
    f16* w2t = (f16*)(ws + 50528256);                 // 37748736 B
    f16* hbuf = (f16*)(ws + 88276992);                // 50331648 B

    hipMemsetAsync(counts, 0, 256, stream);
    hipMemsetAsync(out, 0, (size_t)out_size * sizeof(float), stream);

    router<<<64, 1024, 0, stream>>>(x, gate_w, gate_b, counts, list, wslot);
    scan8<<<1, 64, 0, stream>>>(counts, offs);
    pack_a<<<E_ * N_TOK / 4, 256, 0, stream>>>(x, counts, offs, list, xg);
    cvt_w_t<<<dim3(H_ / 64, D_ / 64, E_), 256, 0, stream>>>(w1, w1t, D_, H_);
    cvt_w_t<<<dim3(D_ / 64, H_ / 64, E_), 256, 0, stream>>>(w2, w2t, H_, D_);
    gemm1<<<E_ * NXB1 * (N_TOK / BT), 256, 0, stream>>>(xg, w1t, b1, counts, offs, hbuf);
    gemm2<<<E_ * NXB2 * (N_TOK / BT), 256, 0, stream>>>(hbuf, w2t, b2, counts, offs, list, wslot, out);
}

// Round 13
// 252.832 us; speedup vs baseline: 1.4789x; 1.0415x over previous
//
#include <hip/hip_runtime.h>
#include <hip/hip_bf16.h>

#define D_ 768
#define E_ 8
#define H_ 3072
#define N_TOK 4096
#define BT 64
#define BK 64

typedef _Float16 f16;
typedef f16 f16x8 __attribute__((ext_vector_type(8)));
typedef float f32x4 __attribute__((ext_vector_type(4)));

__device__ __forceinline__ void gld16(const f16* g, f16* l) {
    __builtin_amdgcn_global_load_lds(
        (const __attribute__((address_space(1))) unsigned int*)g,
        (__attribute__((address_space(3))) unsigned int*)l, 16, 0, 0);
}

__device__ __forceinline__ int prefix_off(const int* counts, int e, int* cnt_out) {
    int off = 0, cnt = 0;
#pragma unroll
    for (int q = 0; q < E_; q++) {
        int cq = counts[q];
        if (q < e) off += cq;
        if (q == e) cnt = cq;
    }
    *cnt_out = cnt;
    return off;
}

// ---------------- combined weight convert+transpose+swizzle (w1 & w2 in one launch) ----------------
// fp32 [R][C] -> fp16 [C][R], output row swizzled in 16B chunks: chunk k at k^(row&7).
__global__ __launch_bounds__(256) void cvt_w_both(const float* __restrict__ w1,
                                                  const float* __restrict__ w2,
                                                  f16* __restrict__ w1t,
                                                  f16* __restrict__ w2t) {
    __shared__ f16 t[64][66];
    int z = blockIdx.z;
    const float* src; f16* dst; int R, C, xb, yb;
    int bx = blockIdx.x;
    if (z < E_) {
        src = w1 + (size_t)z * D_ * H_; dst = w1t + (size_t)z * D_ * H_;
        R = D_; C = H_; xb = bx % 48; yb = bx / 48;        // 48 x, 12 y
    } else {
        src = w2 + (size_t)(z - E_) * H_ * D_; dst = w2t + (size_t)(z - E_) * H_ * D_;
        R = H_; C = D_; xb = bx % 12; yb = bx / 12;        // 12 x, 48 y
    }
    int r0 = yb * 64, c0 = xb * 64;
    int tid = threadIdx.x;
    {
        int r = tid >> 4;
        int c = (tid & 15) * 4;
#pragma unroll
        for (int i = 0; i < 4; i++) {
            float4 v = *(const float4*)(src + (size_t)(r0 + r + i * 16) * C + (c0 + c));
            t[r + i * 16][c] = (f16)v.x;
            t[r + i * 16][c + 1] = (f16)v.y;
            t[r + i * 16][c + 2] = (f16)v.z;
            t[r + i * 16][c + 3] = (f16)v.w;
        }
    }
    __syncthreads();
    {
        int c = tid >> 3;
        int rr = (tid & 7) * 8;
        int ch = rr >> 3;
#pragma unroll
        for (int i = 0; i < 2; i++) {
            int cc = c + i * 32;
            int rowi = c0 + cc;
            f16x8 o;
#pragma unroll
            for (int j = 0; j < 8; j++) o[j] = t[rr + j][cc];
            *(f16x8*)(dst + (size_t)rowi * R + r0 + (((ch ^ rowi) & 7) << 3)) = o;
        }
    }
}

// ---------------- router: coalesced GEMV + LDS-aggregated atomics ----------------
__global__ __launch_bounds__(1024) void router(const float* __restrict__ x,
                                               const float* __restrict__ gw,
                                               const float* __restrict__ gb,
                                               int* __restrict__ counts,
                                               int* __restrict__ list,
                                               float* __restrict__ wslot) {
    __shared__ int lcount[E_];
    __shared__ int lbase[E_];
    __shared__ int te0[64], te1[64], ts0[64], ts1[64];
    __shared__ float tw0[64], tw1[64];

    int tid = threadIdx.x;
    int wv = tid >> 6, lane = tid & 63;
    int s = lane >> 3, eL = lane & 7;
    if (tid < E_) lcount[tid] = 0;
    __syncthreads();

    float biasL = gb[eL];

#pragma unroll 1
    for (int i = 0; i < 4; i++) {
        int lt = wv * 4 + i;
        int tok = blockIdx.x * 64 + lt;
        const float* xr = x + (size_t)tok * D_;
        float a = 0.f;
        const float* gwl = gw + lane;
#pragma unroll 8
        for (int j = 0; j < 96; j++)
            a = fmaf(xr[j * 8 + s], gwl[j * 64], a);
        a += __shfl_xor(a, 8, 64);
        a += __shfl_xor(a, 16, 64);
        a += __shfl_xor(a, 32, 64);
        float lg = a + biasL;
        float le[8];
#pragma unroll
        for (int q = 0; q < 8; q++) le[q] = __shfl(lg, q, 64);
        float v0 = -3.4e38f, v1 = -3.4e38f;
        int i0 = 0, i1 = 0;
#pragma unroll
        for (int q = 0; q < 8; q++) {
            float l = le[q];
            if (l > v0) { v1 = v0; i1 = i0; v0 = l; i0 = q; }
            else if (l > v1) { v1 = l; i1 = q; }
        }
        if (lane == 0) {
            float p1 = expf(v1 - v0);
            float ssum = 1.f + p1;
            int s0 = atomicAdd(&lcount[i0], 1);
            int s1 = atomicAdd(&lcount[i1], 1);
            te0[lt] = i0; ts0[lt] = s0; tw0[lt] = 1.f / ssum;
            te1[lt] = i1; ts1[lt] = s1; tw1[lt] = p1 / ssum;
        }
    }
    __syncthreads();
    if (tid < E_) lbase[tid] = atomicAdd(&counts[tid], lcount[tid]);
    __syncthreads();
    if (tid < 64) {
        int tok = blockIdx.x * 64 + tid;
        int e0 = te0[tid], e1 = te1[tid];
        list[e0 * N_TOK + lbase[e0] + ts0[tid]] = tok * 2;
        list[e1 * N_TOK + lbase[e1] + ts1[tid]] = tok * 2 + 1;
        wslot[tok * 2] = tw0[tid];
        wslot[tok * 2 + 1] = tw1[tid];
    }
}

// ---------------- pack A: gather token rows -> packed swizzled fp16 [8192][D] ----------------
__global__ __launch_bounds__(256) void pack_a(const float* __restrict__ x,
                                              const int* __restrict__ counts,
                                              const int* __restrict__ list,
                                              f16* __restrict__ xg) {
    int wv = threadIdx.x >> 6, lane = threadIdx.x & 63;
    int idx = blockIdx.x * 4 + wv;            // e*N_TOK + j
    int e = idx >> 12, j = idx & (N_TOK - 1);
    int cnt;
    int off = prefix_off(counts, e, &cnt);
    if (j >= cnt) return;
    int id = list[idx];
    int row = off + j;
    const float* xr = x + (size_t)(id >> 1) * D_;
    f16* dst = xg + (size_t)row * D_;
    int r7 = row & 7;
#pragma unroll
    for (int c = 0; c < 3; c++) {
        int h = lane * 4 + c * 256;
        float4 v = *(const float4*)(xr + h);
        f16 o[4] = {(f16)v.x, (f16)v.y, (f16)v.z, (f16)v.w};
        int hs = (h & ~0x3F) | ((((h >> 3) ^ r7) & 7) << 3) | (h & 7);
        *(float2*)(dst + hs) = *(const float2*)o;
    }
}

// ---------------- GEMM1: h = gelu(xg @ w1 + b1), 64x64, gld_lds, XCD-pinned, L2-blocked ----------------
// Within expert: r = xh*(64*24) + yb*24 + xb24  (xh slowest -> 2.25MB B-half stays L2-resident)
__global__ __launch_bounds__(256, 8) void gemm1(const f16* __restrict__ xg,
                                                const f16* __restrict__ w1t,
                                                const float* __restrict__ b1,
                                                const int* __restrict__ counts,
                                                f16* __restrict__ hbuf) {
    int bid = blockIdx.x;
    int e = bid & 7;                 // expert -> XCD (round-robin bid%8)
    int r = bid >> 3;
    int xb24 = r % 24;
    int yb = (r / 24) % 64;
    int xh = r / (24 * 64);          // 0..1
    int cnt;
    int off = prefix_off(counts, e, &cnt);
    int rb = yb * BT;
    if (rb >= cnt) return;
    int cb = (xh * 24 + xb24) * BT;

    __shared__ f16 lds[2 * BT * BK];   // A halfs [0,4096), B halfs [4096,8192)
    char* ldsb = (char*)lds;

    int tid = threadIdx.x;
    int wv = tid >> 6, lane = tid & 63;
    int lr = lane >> 3, lc = lane & 7;

    int r0l = wv * 8 + lr;
    int r1l = 32 + wv * 8 + lr;
    int ag0 = off + rb + r0l; if (ag0 > 8191) ag0 = 8191;
    int ag1 = off + rb + r1l; if (ag1 > 8191) ag1 = 8191;
    const f16* ap0 = xg + (size_t)ag0 * D_ + lc * 8;
    const f16* ap1 = xg + (size_t)ag1 * D_ + lc * 8;
    const f16* wb = w1t + (size_t)e * H_ * D_;
    const f16* bp0 = wb + (size_t)(cb + r0l) * D_ + lc * 8;
    const f16* bp1 = wb + (size_t)(cb + r1l) * D_ + lc * 8;
    f16* la0 = lds + wv * 512;
    f16* la1 = lds + 2048 + wv * 512;
    f16* lb0 = lds + 4096 + wv * 512;
    f16* lb1 = lds + 6144 + wv * 512;

    int wr = (wv >> 1) * 32, wc = (wv & 1) * 32;
    int fr = lane & 15, qh = lane >> 4;
    int koff = (off + rb) & 7;

    int roA[2][2], roB[2][2];
#pragma unroll
    for (int m = 0; m < 2; m++)
#pragma unroll
        for (int ks = 0; ks < 2; ks++) {
            int row = wr + m * 16 + fr;
            roA[m][ks] = row * 128 + ((((ks * 4 + qh) ^ (koff + row)) & 7) << 4);
            int rwb = wc + m * 16 + fr;
            roB[m][ks] = 8192 + rwb * 128 + ((((ks * 4 + qh) ^ rwb) & 7) << 4);
        }

    f32x4 acc[2][2] = {};
    const int NT = D_ / BK;  // 12
#pragma unroll 1
    for (int t = 0; t < NT; ++t) {
        int kk = t * BK;
        gld16(ap0 + kk, la0);
        gld16(ap1 + kk, la1);
        gld16(bp0 + kk, lb0);
        gld16(bp1 + kk, lb1);
        __syncthreads();
#pragma unroll
        for (int ks = 0; ks < 2; ks++) {
            f16x8 a0 = *(const f16x8*)(ldsb + roA[0][ks]);
            f16x8 a1 = *(const f16x8*)(ldsb + roA[1][ks]);
            f16x8 b0 = *(const f16x8*)(ldsb + roB[0][ks]);
            f16x8 b1v = *(const f16x8*)(ldsb + roB[1][ks]);
            acc[0][0] = __builtin_amdgcn_mfma_f32_16x16x32_f16(a0, b0, acc[0][0], 0, 0, 0);
            acc[0][1] = __builtin_amdgcn_mfma_f32_16x16x32_f16(a0, b1v, acc[0][1], 0, 0, 0);
            acc[1][0] = __builtin_amdgcn_mfma_f32_16x16x32_f16(a1, b0, acc[1][0], 0, 0, 0);
            acc[1][1] = __builtin_amdgcn_mfma_f32_16x16x32_f16(a1, b1v, acc[1][1], 0, 0, 0);
        }
        __syncthreads();
    }

#pragma unroll
    for (int n = 0; n < 2; n++) {
        int colg = cb + wc + n * 16 + fr;
        float bias = b1[e * H_ + colg];
#pragma unroll
        for (int m = 0; m < 2; m++) {
#pragma unroll
            for (int r2 = 0; r2 < 4; r2++) {
                int j = rb + wr + m * 16 + qh * 4 + r2;
                if (j < cnt) {
                    float v = acc[m][n][r2] + bias;
                    v = 0.5f * v * (1.f + erff(v * 0.70710678f));
                    int row = off + j;
                    int hs = (colg & ~0x3F) | ((((colg >> 3) ^ row) & 7) << 3) | (colg & 7);
                    hbuf[(size_t)row * H_ + hs] = (f16)v;
                }
            }
        }
    }
}

// ---------------- GEMM2: y = (hbuf @ w2 + b2) * wslot, scatter-add, XCD-pinned, L2-blocked ----------------
// Within expert: r = kz*(64*12) + yb*12 + cb12  (kz slowest -> 2.35MB B-half stays L2-resident)
#define KSPLIT 2
#define KCH (H_ / KSPLIT)
__global__ __launch_bounds__(256, 8) void gemm2(const f16* __restrict__ hbuf,
                                                const f16* __restrict__ w2t,
                                                const float* __restrict__ b2,
                                                const int* __restrict__ counts,
                                                const int* __restrict__ list,
                                                const float* __restrict__ wslot,
                                                float* __restrict__ out) {
    int bid = blockIdx.x;
    int e = bid & 7;                 // expert -> XCD
    int r = bid >> 3;
    int cb12 = r % 12;
    int yb = (r / 12) % 64;
    int kz = r / (12 * 64);          // 0..1
    int cnt;
    int off = prefix_off(counts, e, &cnt);
    int rb = yb * BT;
    if (rb >= cnt) return;
    int cb = cb12 * BT;
    int k0 = kz * KCH;

    __shared__ f16 lds[2 * BT * BK];
    char* ldsb = (char*)lds;

    int tid = threadIdx.x;
    int wv = tid >> 6, lane = tid & 63;
    int lr = lane >> 3, lc = lane & 7;

    int r0l = wv * 8 + lr;
    int r1l = 32 + wv * 8 + lr;
    int ag0 = off + rb + r0l; if (ag0 > 8191) ag0 = 8191;
    int ag1 = off + rb + r1l; if (ag1 > 8191) ag1 = 8191;
    const f16* ap0 = hbuf + (size_t)ag0 * H_ + k0 + lc * 8;
    const f16* ap1 = hbuf + (size_t)ag1 * H_ + k0 + lc * 8;
    const f16* wb = w2t + (size_t)e * D_ * H_;
    const f16* bp0 = wb + (size_t)(cb + r0l) * H_ + k0 + lc * 8;
    const f16* bp1 = wb + (size_t)(cb + r1l) * H_ + k0 + lc * 8;
    f16* la0 = lds + wv * 512;
    f16* la1 = lds + 2048 + wv * 512;
    f16* lb0 = lds + 4096 + wv * 512;
    f16* lb1 = lds + 6144 + wv * 512;

    int wr = (wv >> 1) * 32, wc = (wv & 1) * 32;
    int fr = lane & 15, qh = lane >> 4;
    int koff = (off + rb) & 7;

    int roA[2][2], roB[2][2];
#pragma unroll
    for (int m = 0; m < 2; m++)
#pragma unroll
        for (int ks = 0; ks < 2; ks++) {
            int row = wr + m * 16 + fr;
            roA[m][ks] = row * 128 + ((((ks * 4 + qh) ^ (koff + row)) & 7) << 4);
            int rwb = wc + m * 16 + fr;
            roB[m][ks] = 8192 + rwb * 128 + ((((ks * 4 + qh) ^ rwb) & 7) << 4);
        }

    f32x4 acc[2][2] = {};
    const int NT = KCH / BK;  // 24
#pragma unroll 1
    for (int t = 0; t < NT; ++t) {
        int kk = t * BK;
        gld16(ap0 + kk, la0);
        gld16(ap1 + kk, la1);
        gld16(bp0 + kk, lb0);
        gld16(bp1 + kk, lb1);
        __syncthreads();
#pragma unroll
        for (int ks = 0; ks < 2; ks++) {
            f16x8 a0 = *(const f16x8*)(ldsb + roA[0][ks]);
            f16x8 a1 = *(const f16x8*)(ldsb + roA[1][ks]);
            f16x8 b0 = *(const f16x8*)(ldsb + roB[0][ks]);
            f16x8 b1v = *(const f16x8*)(ldsb + roB[1][ks]);
            acc[0][0] = __builtin_amdgcn_mfma_f32_16x16x32_f16(a0, b0, acc[0][0], 0, 0, 0);
            acc[0][1] = __builtin_amdgcn_mfma_f32_16x16x32_f16(a0, b1v, acc[0][1], 0, 0, 0);
            acc[1][0] = __builtin_amdgcn_mfma_f32_16x16x32_f16(a1, b0, acc[1][0], 0, 0, 0);
            acc[1][1] = __builtin_amdgcn_mfma_f32_16x16x32_f16(a1, b1v, acc[1][1], 0, 0, 0);
        }
        __syncthreads();
    }

#pragma unroll
    for (int n = 0; n < 2; n++) {
        int colg = cb + wc + n * 16 + fr;
        float bias = (kz == 0) ? b2[e * D_ + colg] : 0.f;
#pragma unroll
        for (int m = 0; m < 2; m++) {
#pragma unroll
            for (int r2 = 0; r2 < 4; r2++) {
                int j = rb + wr + m * 16 + qh * 4 + r2;
                if (j < cnt) {
                    int id = list[e * N_TOK + j];
                    float w = wslot[id];
                    float v = (acc[m][n][r2] + bias) * w;
                    atomicAdd(&out[(size_t)(id >> 1) * D_ + colg], v);
                }
            }
        }
    }
}

extern "C" void kernel_launch(void* const* d_in, const int* in_sizes, int n_in,
                              void* d_out, int out_size, void* d_ws, size_t ws_size,
                              hipStream_t stream) {
    const float* x = (const float*)d_in[0];
    const float* gate_w = (const float*)d_in[1];
    const float* gate_b = (const float*)d_in[2];
    const float* w1 = (const float*)d_in[3];
    const float* b1 = (const float*)d_in[4];
    const float* w2 = (const float*)d_in[5];
    const float* b2 = (const float*)d_in[6];
    float* out = (float*)d_out;

    char* ws = (char*)d_ws;
    int* counts = (int*)ws;                           // 32 B
    int* list = (int*)(ws + 1024);                    // 131072 B
    float* wslot = (float*)(ws + 132096);             // 32768 B
    f16* xg = (f16*)(ws + 196608);                    // 12582912 B
    f16* w1t = (f16*)(ws + 12779520);                 // 37748736 B
    f16* w2t = (f16*)(ws + 50528256);                 // 37748736 B
    f16* hbuf = (f16*)(ws + 88276992);                // 50331648 B

    hipMemsetAsync(counts, 0, 256, stream);
    hipMemsetAsync(out, 0, (size_t)out_size * sizeof(float), stream);

    router<<<64, 1024, 0, stream>>>(x, gate_w, gate_b, counts, list, wslot);
    pack_a<<<E_ * N_TOK / 4, 256, 0, stream>>>(x, counts, list, xg);
    cvt_w_both<<<dim3(576, 1, 16), 256, 0, stream>>>(w1, w2, w1t, w2t);
    gemm1<<<E_ * 2 * 64 * 24, 256, 0, stream>>>(xg, w1t, b1, counts, hbuf);
    gemm2<<<E_ * 2 * 64 * 12, 256, 0, stream>>>(hbuf, w2t, b2, counts, list, wslot, out);
}